// Round 9
// baseline (377.760 us; speedup 1.0000x reference)
//
#include <hip/hip_runtime.h>
#include <hip/hip_cooperative_groups.h>
#include <math.h>

namespace cg = cooperative_groups;

#define NSs 6
#define NTs 4
#define Bb  2
#define Nn  32
#define Hh  768
#define Ww  768
#define Rr  28
#define Cch 10
#define NCH 38
#define HW  (Hh*Ww)
#define NEGD (-100.0)
#define NKEY (Nn*Cch + NSs)   // 326: 320 inst-hist keys + 6 stuff counts
// ws ints: [0,640) g_hist[b][n][c] ; [640,652) g_scount[b][s] ; [652,728) lut[b][ch]
#define WS_SC  640
#define WS_LUT 652

struct InstP {
  int y0, x0, y1r, x1r;   // inst box [y0,y1r) x [x0,x1r)
  int ys, ye, xs, xe;     // mask box
  float sc_y, sc_x;       // 28.f/h, 28.f/w
  int tc;                 // NS + cls
  int mskoff;             // offset of selected 28x28 mask
};

__device__ __forceinline__ double sigd(double x) { return 1.0 / (1.0 + exp(-x)); }

// proven fuse+argmax core (bit-exact R1..R7). ch[] constant-indexed after inline.
__device__ __forceinline__ int fuse_px(
    int y, int x, const float (&ch)[Cch], unsigned rel,
    const InstP* __restrict__ spar, const float* __restrict__ roi,
    double EPS, int* smp_out)
{
  int smp = 0; float smv = ch[0];
#pragma unroll
  for (int c = 1; c < Cch; c++) if (ch[c] > smv) { smv = ch[c]; smp = c; }
  *smp_out = smp;

  double m = (double)ch[0]; int pidx = 0;
#pragma unroll
  for (int c = 1; c < NSs; c++) { double v = (double)ch[c]; if (v > m) { m = v; pidx = c; } }

  int next_ch = NSs;
  while (rel) {
    int n = __ffs(rel) - 1; rel &= rel - 1;
    int chn_ = NSs + n;
    if (chn_ > next_ch && EPS > m) { m = EPS; pidx = next_ch; }
    next_ch = chn_ + 1;
    const InstP p = spar[n];
    bool in_i = (y >= p.y0) && (y < p.y1r) && (x >= p.x0) && (x < p.x1r);
    bool in_m = (y >= p.ys) && (y < p.ye)  && (x >= p.xs) && (x < p.xe);
    bool in_any = in_i || in_m;
    if (__any(in_any)) {
      if (in_any) {
        // select chain (NOT ch[p.tc]): dynamic reg-array indexing -> scratch
        int tcl = p.tc;
        float tl = (tcl == 6) ? ch[6] : (tcl == 7) ? ch[7] : (tcl == 8) ? ch[8] : ch[9];
        double iv = in_i ? (double)tl : NEGD;
        double mv = NEGD;
        if (in_m) {
          double syv = ((double)(y - p.y0) + 0.5) * (double)p.sc_y - 0.5;
          double sxv = ((double)(x - p.x0) + 0.5) * (double)p.sc_x - 0.5;
          syv = fmin(fmax(syv, 0.0), 27.0);
          sxv = fmin(fmax(sxv, 0.0), 27.0);
          int iy0 = (int)syv, ix0 = (int)sxv;
          int iy1 = min(iy0 + 1, 27), ix1 = min(ix0 + 1, 27);
          double wy = syv - (double)iy0, wx = sxv - (double)ix0;
          const float* mp = roi + p.mskoff;
          double m00 = (double)mp[iy0*Rr + ix0];
          double m01 = (double)mp[iy0*Rr + ix1];
          double m10 = (double)mp[iy1*Rr + ix0];
          double m11 = (double)mp[iy1*Rr + ix1];
          double c0 = m00*(1.0 - wy) + m10*wy;
          double c1 = m01*(1.0 - wy) + m11*wy;
          mv = c0*(1.0 - wx) + c1*wx;
        }
        double s2 = iv + mv;
        // prune: val = s*s2, s in (0,2]; if fmax(2*s2,0) <= m, val>m impossible
        if (fmax(2.0*s2, 0.0) > m) {
          double val = (sigd(iv) + sigd(mv)) * s2;
          if (val > m) { m = val; pidx = chn_; }
        }
      } else {
        if (EPS > m) { m = EPS; pidx = chn_; }
      }
    } else {
      if (EPS > m) { m = EPS; pidx = chn_; }
    }
  }
  if (next_ch < NCH && EPS > m) { m = EPS; pidx = next_ch; }
  return pidx;
}

__device__ __forceinline__ void setup_inst(
    int b, int n, const float* __restrict__ bbx, const int* __restrict__ cls,
    InstP* spar)
{
  const float* bbp = bbx + ((size_t)b*Nn + n)*4;
  float f0 = bbp[0], f1 = bbp[1], f2 = bbp[2], f3 = bbp[3];
  int y0 = (int)floorf(f0), x0 = (int)floorf(f1);
  int y1 = (int)floorf(f2), x1 = (int)floorf(f3);
  int y1r = (int)(rintf(f2) + 1.0f);   // jnp.round = half-to-even
  int x1r = (int)(rintf(f3) + 1.0f);
  float hh = fmaxf((float)(y1 - y0 + 1), 1.0f);
  float wd = fmaxf((float)(x1 - x0 + 1), 1.0f);
  InstP p;
  p.y0 = y0; p.x0 = x0; p.y1r = y1r; p.x1r = x1r;
  p.ys = max(y0, 0); p.ye = min(y1 + 1, Hh);
  p.xs = max(x0, 0); p.xe = min(x1 + 1, Ww);
  p.sc_y = 28.0f / hh; p.sc_x = 28.0f / wd;
  int cl = cls[b*Nn + n];
  p.tc = NSs + cl;
  p.mskoff = (((b*Nn + n)*NTs) + cl)*Rr*Rr;
  spar[n] = p;
}

// ==== coop kernel: 768 blocks x 256 thr; block y does rows (b0,y),(b1,y) ====
// 3 blocks/CU (host-validated). BARRIER DISCIPLINE (R8 post-mortem): every
// __syncthreads() below is reached by ALL 256 threads — no barrier inside a
// thread-id-divergent branch. Inactive waves compute dummy ballots.
__global__ __launch_bounds__(256, 3) void k_all(
    const float* __restrict__ sem, const float* __restrict__ roi,
    const float* __restrict__ bbx, const int* __restrict__ cls,
    int* __restrict__ out, int* __restrict__ ws)
{
  __shared__ InstP spar[Bb*Nn];
  __shared__ int s_all[Bb*NKEY];
  __shared__ unsigned s_relrow[Bb];
  __shared__ int s_xlo[Bb*Nn], s_xhi[Bb*Nn];
  __shared__ unsigned char s_pb[Bb*Ww];
  __shared__ int slut2[Bb*NCH];
  // phase-2 scratch (block 0 only)
  __shared__ int sh2[WS_LUT];
  __shared__ int spc_s[Bb][NSs];
  __shared__ int pcs[Bb][40];

  cg::grid_group grid = cg::this_grid();

  const int y    = blockIdx.x;           // 0..767
  const int tid  = threadIdx.x;
  const int lane = tid & 63;

  if (tid < Bb) s_relrow[tid] = 0u;      // wave 0, before wave-0 atomicOr: program order
  for (int i = tid; i < Bb*NKEY; i += 256) s_all[i] = 0;
  if (tid < Bb*Nn) {
    const int bb = tid >> 5, n = tid & 31;
    setup_inst(bb, n, bbx, cls, spar + bb*Nn);
    const InstP p = spar[tid];
    s_xlo[tid] = min(p.x0, p.xs);        // union x-interval (conservative gate)
    s_xhi[tid] = max(p.x1r, p.xe);
    bool rowi = (y >= p.y0) && (y < p.y1r);
    bool rowm = (y >= p.ys) && (y < p.ye);
    if (rowi || rowm) atomicOr(&s_relrow[bb], 1u << n);
  }
  __syncthreads();

  const double EPS = (sigd(NEGD) + sigd(NEGD)) * (NEGD + NEGD);

  // gating regs: every wave's lane l watches (batch l>>5, inst l&31)
  const int  gb   = lane >> 5;
  const int  gxlo = s_xlo[lane];
  const int  gxhi = s_xhi[lane];
  const bool grow = (s_relrow[gb] >> (lane & 31)) & 1u;

  // ---- phase 1: fuse both rows, pidx -> LDS bytes, hist -> LDS ----
  for (int bb = 0; bb < Bb; bb++) {
    const float* base = sem + (size_t)bb*Cch*HW + (size_t)y*Ww;
    const InstP* sp = spar + bb*Nn;
    float cur[Cch], nxt[Cch];
#pragma unroll
    for (int c = 0; c < Cch; c++) cur[c] = base[(size_t)c*HW + tid];
    for (int ck = 0; ck < 3; ck++) {
      const int x = ck*256 + tid;
      if (ck < 2) {
#pragma unroll
        for (int c = 0; c < Cch; c++) nxt[c] = base[(size_t)c*HW + x + 256];
      }
      const int xa = x & ~63;    // wave's 64-px window (uniform per wave)
      unsigned long long ball = __ballot(grow && (gxlo < xa + 64) && (gxhi > xa));
      unsigned relw = (unsigned)(ball >> (32*bb));   // this batch's watcher lanes

      int smp;
      int pidx = fuse_px(y, x, cur, relw, sp, roi, EPS, &smp);
      s_pb[bb*Ww + x] = (unsigned char)pidx;
      atomicAdd(&s_all[bb*NKEY + ((pidx >= NSs) ? ((pidx - NSs)*Cch + smp)
                                                : (Nn*Cch + pidx))], 1);
      if (ck < 2) {
#pragma unroll
        for (int c = 0; c < Cch; c++) cur[c] = nxt[c];
      }
    }
  }
  __syncthreads();
  for (int i = tid; i < Bb*NKEY; i += 256) {
    int v = s_all[i];
    if (v) {
      int bb = i / NKEY, k = i - bb*NKEY;
      if (k < Nn*Cch) atomicAdd(&ws[bb*Nn*Cch + k], v);
      else            atomicAdd(&ws[WS_SC + bb*NSs + (k - Nn*Cch)], v);
    }
  }
  __threadfence();
  grid.sync();

  // ---- phase 2: block 0, ballot/popcount post logic; barriers uniform ----
  if (blockIdx.x == 0) {
    for (int i = tid; i < WS_LUT; i += 256) sh2[i] = ws[i];
    __syncthreads();                       // ALL 256 threads
    const int  b   = tid >> 6;             // waves 2,3: b=2,3 -> inactive (bv=false)
    const int  ln  = tid & 63;
    const int  bs  = b & 1;                // safe LDS index for inactive waves
    const bool bv  = b < Bb;
    const bool act = bv && (ln < Nn);
    if (bv && ln < NSs) spc_s[b][ln] = sh2[WS_SC + b*NSs + ln];
    __syncthreads();
    int total = 0, mi = 0, mx = -1, tmp = 0;
    bool br2 = false, kept = false;
    if (act) {
      const int* hb = sh2 + b*Nn*Cch + ln*Cch;
#pragma unroll
      for (int c = 0; c < Cch; c++) { int v = hb[c]; total += v; if (v > mx) { mx = v; mi = c; } }
      tmp = cls[b*Nn + ln] + NSs;
      bool present = total > 0;
      bool b1 = (mi == tmp);
      br2  = (!b1) && (2*mx >= total) && (mi < NSs) && present;
      kept = present && !br2;
      if (br2) atomicAdd(&spc_s[b][mi], total);
    }
    __syncthreads();
    unsigned mask6 = (unsigned)(__ballot(bv && ln < NSs && spc_s[bs][ln] > 0) & 0x3Full);
    int nstuff = __popc(mask6);
    unsigned kmask = (unsigned)(__ballot(act && kept) & 0xFFFFFFFFull);
    int nk = __popc(kmask);
    int vlen = 1 + nstuff + nk;

    if (bv && ln < NSs)
      ws[WS_LUT + b*NCH + ln] = __popc(mask6 & ((1u << ln) - 1)) + 1;  // absent: unused
    if (act) {
      int rk  = __popc(kmask & ((1u << ln) - 1));
      int srk = __popc(mask6 & ((1u << mi) - 1));
      ws[WS_LUT + b*NCH + NSs + ln] = kept ? (1 + nstuff + rk) : (br2 ? srk + 1 : 0);
    }
    if (bv && ln < 39) pcs[b][ln] = -1;
    __syncthreads();
    if (bv && ln == 0) pcs[b][0] = 255;
    if (bv && ln < NSs && ((mask6 >> ln) & 1))
      pcs[b][1 + __popc(mask6 & ((1u << ln) - 1))] = ln;
    if (act && kept)
      pcs[b][1 + nstuff + __popc(kmask & ((1u << ln) - 1))] = tmp;
    __syncthreads();
    int* pc = out + (size_t)Bb*HW;       // po_cls   [Bb][39]
    int* ic = pc + Bb*39;                // iscrowd  [Bb][39]
    int* vl = ic + Bb*39;                // valid_len[Bb]
    if (bv && ln < 39) {
      pc[b*39 + ln] = pcs[b][ln];
      ic[b*39 + ln] = (ln < vlen) ? 0 : -1;
    }
    if (bv && ln == 0) vl[b] = vlen;
  }
  __threadfence();
  grid.sync();

  // ---- phase 3: map LDS pidx bytes through LUT, single output write ----
  if (tid < Bb*NCH) slut2[tid] = ws[WS_LUT + tid];
  __syncthreads();
#pragma unroll
  for (int bb = 0; bb < Bb; bb++)
    for (int ck = 0; ck < 3; ck++) {
      int x = ck*256 + tid;
      out[(size_t)bb*HW + (size_t)y*Ww + x] = slut2[bb*NCH + s_pb[bb*Ww + x]];
    }
}

// ===================== fallback: proven R7 4-kernel path =====================
__global__ void k_zero(int* __restrict__ p, int n) {
  for (int i = threadIdx.x; i < n; i += 256) p[i] = 0;
}

__global__ __launch_bounds__(256) void k_fuse(
    const float* __restrict__ sem, const float* __restrict__ roi,
    const float* __restrict__ bbx, const int* __restrict__ cls,
    int* __restrict__ out_pred, int* __restrict__ g_hist, int* __restrict__ g_scount)
{
  __shared__ InstP spar[Nn];
  __shared__ int s_all[NKEY];
  __shared__ unsigned s_rel;
  __shared__ int s_xlo[Nn], s_xhi[Nn];

  const int bid  = blockIdx.x;
  const int y    = bid % Hh;
  const int b    = bid / Hh;
  const int tid  = threadIdx.x;
  const int lane = tid & 63;

  if (tid == 0) s_rel = 0u;
  for (int i = tid; i < NKEY; i += 256) s_all[i] = 0;
  if (tid < Nn) {
    setup_inst(b, tid, bbx, cls, spar);
    const InstP p = spar[tid];
    s_xlo[tid] = min(p.x0, p.xs);
    s_xhi[tid] = max(p.x1r, p.xe);
    bool rowi = (y >= p.y0) && (y < p.y1r);
    bool rowm = (y >= p.ys) && (y < p.ye);
    if (rowi || rowm) atomicOr(&s_rel, 1u << tid);
  }
  __syncthreads();

  const double EPS = (sigd(NEGD) + sigd(NEGD)) * (NEGD + NEGD);
  const float* base = sem + (size_t)b*Cch*HW + (size_t)y*Ww;

  const int  li   = lane & 31;
  const int  gxlo = s_xlo[li];
  const int  gxhi = s_xhi[li];
  const bool grow = (lane < 32) && ((s_rel >> li) & 1u);

  float cur[Cch], nxt[Cch];
#pragma unroll
  for (int c = 0; c < Cch; c++) cur[c] = base[(size_t)c*HW + tid];

  for (int ck = 0; ck < 3; ck++) {
    const int x = ck*256 + tid;
    if (ck < 2) {
#pragma unroll
      for (int c = 0; c < Cch; c++) nxt[c] = base[(size_t)c*HW + x + 256];
    }
    const int xa = x & ~63;
    unsigned relw = (unsigned)__ballot(grow && (gxlo < xa + 64) && (gxhi > xa));

    int smp;
    int pidx = fuse_px(y, x, cur, relw, spar, roi, EPS, &smp);
    out_pred[(size_t)b*HW + (size_t)y*Ww + x] = pidx;
    atomicAdd(&s_all[(pidx >= NSs) ? ((pidx - NSs)*Cch + smp) : (Nn*Cch + pidx)], 1);

    if (ck < 2) {
#pragma unroll
      for (int c = 0; c < Cch; c++) cur[c] = nxt[c];
    }
  }

  __syncthreads();
  for (int i = tid; i < NKEY; i += 256) {
    int v = s_all[i];
    if (v) {
      if (i < Nn*Cch) atomicAdd(&g_hist[b*Nn*Cch + i], v);
      else            atomicAdd(&g_scount[b*NSs + (i - Nn*Cch)], v);
    }
  }
}

__global__ __launch_bounds__(128) void k_post(
    const int* __restrict__ g_hist, const int* __restrict__ g_scount,
    const int* __restrict__ cls, int* __restrict__ lut,
    int* __restrict__ out_tail)
{
  __shared__ int sh[Bb*Nn*Cch];
  __shared__ int spc_f[Bb][NSs];
  __shared__ int pcf[Bb][40];
  const int t = threadIdx.x;
  for (int i = t; i < Bb*Nn*Cch; i += 128) sh[i] = g_hist[i];
  if (t < Bb*NSs) spc_f[t/NSs][t%NSs] = g_scount[t];
  __syncthreads();

  const int b    = t >> 6;
  const int lane = t & 63;
  const bool act = lane < Nn;

  int total = 0, mi = 0, mx = -1, tmp = 0;
  bool br2 = false, kept = false;
  if (act) {
    const int* hb = sh + b*Nn*Cch + lane*Cch;
#pragma unroll
    for (int c = 0; c < Cch; c++) { int v = hb[c]; total += v; if (v > mx) { mx = v; mi = c; } }
    tmp = cls[b*Nn + lane] + NSs;
    bool present = total > 0;
    bool b1 = (mi == tmp);
    br2  = (!b1) && (2*mx >= total) && (mi < NSs) && present;
    kept = present && !br2;
    if (br2) atomicAdd(&spc_f[b][mi], total);
  }
  __syncthreads();

  unsigned mask6 = (unsigned)(__ballot(lane < NSs && spc_f[b][lane] > 0) & 0x3Full);
  int nstuff = __popc(mask6);
  unsigned kmask = (unsigned)(__ballot(act && kept) & 0xFFFFFFFFull);
  int nk = __popc(kmask);
  int vlen = 1 + nstuff + nk;

  if (lane < NSs) lut[b*NCH + lane] = __popc(mask6 & ((1u << lane) - 1)) + 1;
  if (act) {
    int rk     = __popc(kmask & ((1u << lane) - 1));
    int srk_mi = __popc(mask6 & ((1u << mi) - 1));
    lut[b*NCH + NSs + lane] = kept ? (1 + nstuff + rk) : (br2 ? srk_mi + 1 : 0);
  }

  if (lane < 39) pcf[b][lane] = -1;
  __syncthreads();
  if (lane == 0) pcf[b][0] = 255;
  if (lane < NSs && ((mask6 >> lane) & 1))
    pcf[b][1 + __popc(mask6 & ((1u << lane) - 1))] = lane;
  if (act && kept)
    pcf[b][1 + nstuff + __popc(kmask & ((1u << lane) - 1))] = tmp;
  __syncthreads();

  int* pc = out_tail;
  int* ic = out_tail + Bb*39;
  int* vl = out_tail + 2*Bb*39;
  if (lane < 39) {
    pc[b*39 + lane] = pcf[b][lane];
    ic[b*39 + lane] = (lane < vlen) ? 0 : -1;
  }
  if (lane == 0) vl[b] = vlen;
}

__global__ __launch_bounds__(256) void k_seam(int* __restrict__ pred, const int* __restrict__ lut)
{
  __shared__ int slut[Bb*NCH];
  int tid = threadIdx.x;
  if (tid < Bb*NCH) slut[tid] = lut[tid];
  __syncthreads();
  size_t i = ((size_t)blockIdx.x*256 + tid) * 4;
  int b = (int)(i / HW);
  int4 v = *reinterpret_cast<int4*>(pred + i);
  int base = b*NCH;
  v.x = slut[base + v.x];
  v.y = slut[base + v.y];
  v.z = slut[base + v.z];
  v.w = slut[base + v.w];
  *reinterpret_cast<int4*>(pred + i) = v;
}

extern "C" void kernel_launch(void* const* d_in, const int* in_sizes, int n_in,
                              void* d_out, int out_size, void* d_ws, size_t ws_size,
                              hipStream_t stream)
{
  const float* sem = (const float*)d_in[0];
  const float* roi = (const float*)d_in[1];
  const float* bbx = (const float*)d_in[2];
  const int*   cls = (const int*)d_in[3];
  int* out = (int*)d_out;
  int* wsI = (int*)d_ws;

  // coop path: host-validated occupancy (need 3 blocks/CU for 768 blocks),
  // error-checked launch, deterministic decision per process.
  int maxB = 0;
  hipError_t e = hipOccupancyMaxActiveBlocksPerMultiprocessor(
      &maxB, (const void*)k_all, 256, 0);
  bool ok = (e == hipSuccess) && (maxB >= 3) &&
            (ws_size >= (size_t)(WS_LUT + Bb*NCH)*4);
  if (ok) {
    hipMemsetAsync(wsI, 0, WS_LUT*sizeof(int), stream);   // hist+scount zero
    void* args[] = { (void*)&sem, (void*)&roi, (void*)&bbx, (void*)&cls,
                     (void*)&out, (void*)&wsI };
    ok = hipLaunchCooperativeKernel((const void*)k_all, dim3(Hh), dim3(256),
                                    args, 0, stream) == hipSuccess;
  }
  if (!ok) {
    int* g_hist   = wsI;                        // Bb*Nn*Cch = 640
    int* g_scount = g_hist + Bb*Nn*Cch;         // Bb*NSs   = 12
    int* lut      = g_scount + Bb*NSs;          // Bb*NCH   = 76
    k_zero<<<1, 256, 0, stream>>>(g_hist, Bb*Nn*Cch + Bb*NSs);
    k_fuse<<<dim3(Bb*Hh), 256, 0, stream>>>(sem, roi, bbx, cls, out, g_hist, g_scount);
    k_post<<<1, 128, 0, stream>>>(g_hist, g_scount, cls, lut, out + (size_t)Bb*HW);
    k_seam<<<dim3((Bb*HW)/(256*4)), 256, 0, stream>>>(out, lut);
  }
}

// Round 11
// 132.632 us; speedup vs baseline: 2.8482x; 2.8482x over previous
//
#include <hip/hip_runtime.h>
#include <math.h>

#define NSs 6
#define NTs 4
#define Bb  2
#define Nn  32
#define Hh  768
#define Ww  768
#define Rr  28
#define Cch 10
#define NCH 38
#define HW  (Hh*Ww)
#define NEGD (-100.0)
#define NKEY (Nn*Cch + NSs)   // 326: 320 inst-hist keys + 6 stuff counts

struct InstP {
  int y0, x0, y1r, x1r;   // inst box [y0,y1r) x [x0,x1r)
  int ys, ye, xs, xe;     // mask box
  float sc_y, sc_x;       // 28.f/h, 28.f/w
  int tc;                 // NS + cls
  int mskoff;             // offset of selected 28x28 mask
};

__device__ __forceinline__ double sigd(double x) { return 1.0 / (1.0 + exp(-x)); }

// proven fuse+argmax core (bit-exact R1..R9). ch[] constant-indexed after inline.
__device__ __forceinline__ int fuse_px(
    int y, int x, const float (&ch)[Cch], unsigned rel,
    const InstP* __restrict__ spar, const float* __restrict__ roi,
    double EPS, int* smp_out)
{
  int smp = 0; float smv = ch[0];
#pragma unroll
  for (int c = 1; c < Cch; c++) if (ch[c] > smv) { smv = ch[c]; smp = c; }
  *smp_out = smp;

  double m = (double)ch[0]; int pidx = 0;
#pragma unroll
  for (int c = 1; c < NSs; c++) { double v = (double)ch[c]; if (v > m) { m = v; pidx = c; } }

  int next_ch = NSs;
  while (rel) {
    int n = __ffs(rel) - 1; rel &= rel - 1;
    int chn_ = NSs + n;
    if (chn_ > next_ch && EPS > m) { m = EPS; pidx = next_ch; }
    next_ch = chn_ + 1;
    const InstP p = spar[n];
    bool in_i = (y >= p.y0) && (y < p.y1r) && (x >= p.x0) && (x < p.x1r);
    bool in_m = (y >= p.ys) && (y < p.ye)  && (x >= p.xs) && (x < p.xe);
    bool in_any = in_i || in_m;
    if (__any(in_any)) {
      if (in_any) {
        // select chain (NOT ch[p.tc]): dynamic reg-array indexing -> scratch
        int tcl = p.tc;
        float tl = (tcl == 6) ? ch[6] : (tcl == 7) ? ch[7] : (tcl == 8) ? ch[8] : ch[9];
        double iv = in_i ? (double)tl : NEGD;
        double mv = NEGD;
        if (in_m) {
          double syv = ((double)(y - p.y0) + 0.5) * (double)p.sc_y - 0.5;
          double sxv = ((double)(x - p.x0) + 0.5) * (double)p.sc_x - 0.5;
          syv = fmin(fmax(syv, 0.0), 27.0);
          sxv = fmin(fmax(sxv, 0.0), 27.0);
          int iy0 = (int)syv, ix0 = (int)sxv;
          int iy1 = min(iy0 + 1, 27), ix1 = min(ix0 + 1, 27);
          double wy = syv - (double)iy0, wx = sxv - (double)ix0;
          const float* mp = roi + p.mskoff;
          double m00 = (double)mp[iy0*Rr + ix0];
          double m01 = (double)mp[iy0*Rr + ix1];
          double m10 = (double)mp[iy1*Rr + ix0];
          double m11 = (double)mp[iy1*Rr + ix1];
          double c0 = m00*(1.0 - wy) + m10*wy;
          double c1 = m01*(1.0 - wy) + m11*wy;
          mv = c0*(1.0 - wx) + c1*wx;
        }
        double s2 = iv + mv;
        // prune: val = s*s2, s in (0,2]; if fmax(2*s2,0) <= m, val>m impossible
        if (fmax(2.0*s2, 0.0) > m) {
          double val = (sigd(iv) + sigd(mv)) * s2;
          if (val > m) { m = val; pidx = chn_; }
        }
      } else {
        if (EPS > m) { m = EPS; pidx = chn_; }
      }
    } else {
      if (EPS > m) { m = EPS; pidx = chn_; }
    }
  }
  if (next_ch < NCH && EPS > m) { m = EPS; pidx = next_ch; }
  return pidx;
}

__device__ __forceinline__ void setup_inst(
    int b, int n, const float* __restrict__ bbx, const int* __restrict__ cls,
    InstP* spar)
{
  const float* bbp = bbx + ((size_t)b*Nn + n)*4;
  float f0 = bbp[0], f1 = bbp[1], f2 = bbp[2], f3 = bbp[3];
  int y0 = (int)floorf(f0), x0 = (int)floorf(f1);
  int y1 = (int)floorf(f2), x1 = (int)floorf(f3);
  int y1r = (int)(rintf(f2) + 1.0f);   // jnp.round = half-to-even
  int x1r = (int)(rintf(f3) + 1.0f);
  float hh = fmaxf((float)(y1 - y0 + 1), 1.0f);
  float wd = fmaxf((float)(x1 - x0 + 1), 1.0f);
  InstP p;
  p.y0 = y0; p.x0 = x0; p.y1r = y1r; p.x1r = x1r;
  p.ys = max(y0, 0); p.ye = min(y1 + 1, Hh);
  p.xs = max(x0, 0); p.xe = min(x1 + 1, Ww);
  p.sc_y = 28.0f / hh; p.sc_x = 28.0f / wd;
  int cl = cls[b*Nn + n];
  p.tc = NSs + cl;
  p.mskoff = (((b*Nn + n)*NTs) + cl)*Rr*Rr;
  spar[n] = p;
}

__global__ void k_zero(int* __restrict__ p, int n) {
  for (int i = threadIdx.x; i < n; i += 256) p[i] = 0;
}

// grid = B*H = 1536 row blocks; 192 threads x 4 px via float4 channel loads
// (10 dwordx4 vs 30 dword) and one coalesced int4 pred store.
// R10 post-mortem: the stray per-k vout.x=0 clobber is REMOVED; vout is
// initialized once before the loop and each field written exactly once.
__global__ __launch_bounds__(192) void k_fuse(
    const float* __restrict__ sem, const float* __restrict__ roi,
    const float* __restrict__ bbx, const int* __restrict__ cls,
    int* __restrict__ out_pred, int* __restrict__ g_hist, int* __restrict__ g_scount)
{
  __shared__ InstP spar[Nn];
  __shared__ int s_all[NKEY];
  __shared__ unsigned s_rel;
  __shared__ int s_xlo[Nn], s_xhi[Nn];

  const int bid  = blockIdx.x;
  const int y    = bid % Hh;
  const int b    = bid / Hh;
  const int tid  = threadIdx.x;
  const int lane = tid & 63;

  if (tid == 0) s_rel = 0u;
  for (int i = tid; i < NKEY; i += 192) s_all[i] = 0;
  if (tid < Nn) {
    setup_inst(b, tid, bbx, cls, spar);
    const InstP p = spar[tid];
    s_xlo[tid] = min(p.x0, p.xs);        // union x-interval (conservative gate)
    s_xhi[tid] = max(p.x1r, p.xe);
    bool rowi = (y >= p.y0) && (y < p.y1r);
    bool rowm = (y >= p.ys) && (y < p.ye);
    if (rowi || rowm) atomicOr(&s_rel, 1u << tid);
  }
  __syncthreads();

  const double EPS = (sigd(NEGD) + sigd(NEGD)) * (NEGD + NEGD);
  const float* base = sem + (size_t)b*Cch*HW + (size_t)y*Ww;

  float4 cur[Cch];
#pragma unroll
  for (int c = 0; c < Cch; c++)
    cur[c] = *reinterpret_cast<const float4*>(base + (size_t)c*HW + 4*tid);

  // per-wave 256-px window gating (lane l < 32 watches instance l)
  const int  li   = lane & 31;
  const int  gxlo = s_xlo[li];
  const int  gxhi = s_xhi[li];
  const bool grow = (lane < 32) && ((s_rel >> li) & 1u);
  const int  wb   = (tid >> 6) << 8;     // wave w covers px [256w, 256w+256)
  const unsigned relw =
      (unsigned)__ballot(grow && (gxlo < wb + 256) && (gxhi > wb));

  int4 vout = make_int4(0, 0, 0, 0);
#pragma unroll
  for (int k = 0; k < 4; k++) {
    float ch[Cch];
#pragma unroll
    for (int c = 0; c < Cch; c++)
      ch[c] = (k == 0) ? cur[c].x : (k == 1) ? cur[c].y : (k == 2) ? cur[c].z : cur[c].w;
    const int x = 4*tid + k;
    int smp;
    int pidx = fuse_px(y, x, ch, relw, spar, roi, EPS, &smp);
    if (k == 0) vout.x = pidx; else if (k == 1) vout.y = pidx;
    else if (k == 2) vout.z = pidx; else vout.w = pidx;
    atomicAdd(&s_all[(pidx >= NSs) ? ((pidx - NSs)*Cch + smp) : (Nn*Cch + pidx)], 1);
  }
  *reinterpret_cast<int4*>(out_pred + (size_t)b*HW + (size_t)y*Ww + 4*tid) = vout;

  __syncthreads();
  for (int i = tid; i < NKEY; i += 192) {
    int v = s_all[i];
    if (v) {
      if (i < Nn*Cch) atomicAdd(&g_hist[b*Nn*Cch + i], v);
      else            atomicAdd(&g_scount[b*NSs + (i - Nn*Cch)], v);
    }
  }
}

// merged post+seam: every block recomputes the tiny post logic from the
// L2-hot 652-int hist (ballot/popcount, no scratch), builds slut in LDS,
// block 0 also writes po_cls/iscrowd/valid_len, then int4-remaps its slice.
// All __syncthreads() reached by ALL 256 threads (R8 post-mortem).
__global__ __launch_bounds__(256) void k_seam2(
    int* __restrict__ pred, const int* __restrict__ g_hist,
    const int* __restrict__ g_scount, const int* __restrict__ cls,
    int* __restrict__ out_tail)
{
  __shared__ int sh[Bb*Nn*Cch];
  __shared__ int spc_f[Bb][NSs];
  __shared__ int pcf[Bb][40];
  __shared__ int slut[Bb*NCH];
  const int t = threadIdx.x;
  for (int i = t; i < Bb*Nn*Cch; i += 256) sh[i] = g_hist[i];
  if (t < Bb*NSs) spc_f[t/NSs][t%NSs] = g_scount[t];
  __syncthreads();

  const int  b    = t >> 6;        // waves 2,3 inactive (bv=false), barrier-uniform
  const int  lane = t & 63;
  const int  bs   = b & 1;         // safe LDS index for inactive waves
  const bool bv   = b < Bb;
  const bool act  = bv && (lane < Nn);

  int total = 0, mi = 0, mx = -1, tmp = 0;
  bool br2 = false, kept = false;
  if (act) {
    const int* hb = sh + b*Nn*Cch + lane*Cch;
#pragma unroll
    for (int c = 0; c < Cch; c++) { int v = hb[c]; total += v; if (v > mx) { mx = v; mi = c; } }
    tmp = cls[b*Nn + lane] + NSs;
    bool present = total > 0;
    bool b1 = (mi == tmp);
    br2  = (!b1) && (2*mx >= total) && (mi < NSs) && present;
    kept = present && !br2;
    if (br2) atomicAdd(&spc_f[b][mi], total);
  }
  __syncthreads();

  unsigned mask6 = (unsigned)(__ballot(bv && lane < NSs && spc_f[bs][lane] > 0) & 0x3Full);
  int nstuff = __popc(mask6);
  unsigned kmask = (unsigned)(__ballot(act && kept) & 0xFFFFFFFFull);
  int nk = __popc(kmask);
  int vlen = 1 + nstuff + nk;

  if (bv && lane < NSs)
    slut[b*NCH + lane] = __popc(mask6 & ((1u << lane) - 1)) + 1;  // absent: unused
  if (act) {
    int rk     = __popc(kmask & ((1u << lane) - 1));
    int srk_mi = __popc(mask6 & ((1u << mi) - 1));
    slut[b*NCH + NSs + lane] = kept ? (1 + nstuff + rk) : (br2 ? srk_mi + 1 : 0);
  }
  if (bv && lane < 39) pcf[b][lane] = -1;
  __syncthreads();
  if (bv && lane == 0) pcf[b][0] = 255;
  if (bv && lane < NSs && ((mask6 >> lane) & 1))
    pcf[b][1 + __popc(mask6 & ((1u << lane) - 1))] = lane;
  if (act && kept)
    pcf[b][1 + nstuff + __popc(kmask & ((1u << lane) - 1))] = tmp;
  __syncthreads();

  if (blockIdx.x == 0) {               // tail written once (no barriers inside)
    int* pc = out_tail;                // po_cls   [Bb][39]
    int* ic = out_tail + Bb*39;        // iscrowd  [Bb][39]
    int* vl = out_tail + 2*Bb*39;      // valid_len[Bb]
    if (bv && lane < 39) {
      pc[b*39 + lane] = pcf[b][lane];
      ic[b*39 + lane] = (lane < vlen) ? 0 : -1;
    }
    if (bv && lane == 0) vl[b] = vlen;
  }

  size_t i = ((size_t)blockIdx.x*256 + t) * 4;
  int bb = (int)(i / HW);              // HW divisible by 4: no straddle
  int4 v = *reinterpret_cast<int4*>(pred + i);
  int bo = bb*NCH;
  v.x = slut[bo + v.x];
  v.y = slut[bo + v.y];
  v.z = slut[bo + v.z];
  v.w = slut[bo + v.w];
  *reinterpret_cast<int4*>(pred + i) = v;
}

extern "C" void kernel_launch(void* const* d_in, const int* in_sizes, int n_in,
                              void* d_out, int out_size, void* d_ws, size_t ws_size,
                              hipStream_t stream)
{
  const float* sem = (const float*)d_in[0];
  const float* roi = (const float*)d_in[1];
  const float* bbx = (const float*)d_in[2];
  const int*   cls = (const int*)d_in[3];
  int* out = (int*)d_out;

  int* g_hist   = (int*)d_ws;                 // Bb*Nn*Cch = 640
  int* g_scount = g_hist + Bb*Nn*Cch;         // Bb*NSs   = 12

  k_zero<<<1, 256, 0, stream>>>(g_hist, Bb*Nn*Cch + Bb*NSs);
  k_fuse<<<dim3(Bb*Hh), 192, 0, stream>>>(sem, roi, bbx, cls, out, g_hist, g_scount);
  k_seam2<<<dim3((Bb*HW)/(256*4)), 256, 0, stream>>>(out, g_hist, g_scount, cls,
                                                     out + (size_t)Bb*HW);
}

// Round 12
// 109.597 us; speedup vs baseline: 3.4468x; 1.2102x over previous
//
#include <hip/hip_runtime.h>
#include <math.h>

#define NSs 6
#define NTs 4
#define Bb  2
#define Nn  32
#define Hh  768
#define Ww  768
#define Rr  28
#define Cch 10
#define NCH 38
#define HW  (Hh*Ww)
#define NEGD (-100.0)
#define NKEY (Nn*Cch + NSs)   // 326: 320 inst-hist keys + 6 stuff counts

struct InstP {
  int y0, x0, y1r, x1r;   // inst box [y0,y1r) x [x0,x1r)
  int ys, ye, xs, xe;     // mask box
  float sc_y, sc_x;       // 28.f/h, 28.f/w
  int tc;                 // NS + cls
  int mskoff;             // offset of selected 28x28 mask
};

__device__ __forceinline__ double sigd(double x) { return 1.0 / (1.0 + exp(-x)); }

// proven fuse+argmax core (bit-exact R1..R11). ch[] constant-indexed after inline.
__device__ __forceinline__ int fuse_px(
    int y, int x, const float (&ch)[Cch], unsigned rel,
    const InstP* __restrict__ spar, const float* __restrict__ roi,
    double EPS, int* smp_out)
{
  int smp = 0; float smv = ch[0];
#pragma unroll
  for (int c = 1; c < Cch; c++) if (ch[c] > smv) { smv = ch[c]; smp = c; }
  *smp_out = smp;

  double m = (double)ch[0]; int pidx = 0;
#pragma unroll
  for (int c = 1; c < NSs; c++) { double v = (double)ch[c]; if (v > m) { m = v; pidx = c; } }

  int next_ch = NSs;
  while (rel) {
    int n = __ffs(rel) - 1; rel &= rel - 1;
    int chn_ = NSs + n;
    if (chn_ > next_ch && EPS > m) { m = EPS; pidx = next_ch; }
    next_ch = chn_ + 1;
    const InstP p = spar[n];
    bool in_i = (y >= p.y0) && (y < p.y1r) && (x >= p.x0) && (x < p.x1r);
    bool in_m = (y >= p.ys) && (y < p.ye)  && (x >= p.xs) && (x < p.xe);
    bool in_any = in_i || in_m;
    if (__any(in_any)) {            // wave lanes = contiguous 64-px window
      if (in_any) {
        // select chain (NOT ch[p.tc]): dynamic reg-array indexing -> scratch
        int tcl = p.tc;
        float tl = (tcl == 6) ? ch[6] : (tcl == 7) ? ch[7] : (tcl == 8) ? ch[8] : ch[9];
        double iv = in_i ? (double)tl : NEGD;
        double mv = NEGD;
        if (in_m) {
          double syv = ((double)(y - p.y0) + 0.5) * (double)p.sc_y - 0.5;
          double sxv = ((double)(x - p.x0) + 0.5) * (double)p.sc_x - 0.5;
          syv = fmin(fmax(syv, 0.0), 27.0);
          sxv = fmin(fmax(sxv, 0.0), 27.0);
          int iy0 = (int)syv, ix0 = (int)sxv;
          int iy1 = min(iy0 + 1, 27), ix1 = min(ix0 + 1, 27);
          double wy = syv - (double)iy0, wx = sxv - (double)ix0;
          const float* mp = roi + p.mskoff;
          double m00 = (double)mp[iy0*Rr + ix0];
          double m01 = (double)mp[iy0*Rr + ix1];
          double m10 = (double)mp[iy1*Rr + ix0];
          double m11 = (double)mp[iy1*Rr + ix1];
          double c0 = m00*(1.0 - wy) + m10*wy;
          double c1 = m01*(1.0 - wy) + m11*wy;
          mv = c0*(1.0 - wx) + c1*wx;
        }
        double s2 = iv + mv;
        // prune: val = s*s2, s in (0,2]; if fmax(2*s2,0) <= m, val>m impossible
        if (fmax(2.0*s2, 0.0) > m) {
          double val = (sigd(iv) + sigd(mv)) * s2;
          if (val > m) { m = val; pidx = chn_; }
        }
      } else {
        if (EPS > m) { m = EPS; pidx = chn_; }
      }
    } else {
      if (EPS > m) { m = EPS; pidx = chn_; }
    }
  }
  if (next_ch < NCH && EPS > m) { m = EPS; pidx = next_ch; }
  return pidx;
}

__device__ __forceinline__ void setup_inst(
    int b, int n, const float* __restrict__ bbx, const int* __restrict__ cls,
    InstP* spar)
{
  const float* bbp = bbx + ((size_t)b*Nn + n)*4;
  float f0 = bbp[0], f1 = bbp[1], f2 = bbp[2], f3 = bbp[3];
  int y0 = (int)floorf(f0), x0 = (int)floorf(f1);
  int y1 = (int)floorf(f2), x1 = (int)floorf(f3);
  int y1r = (int)(rintf(f2) + 1.0f);   // jnp.round = half-to-even
  int x1r = (int)(rintf(f3) + 1.0f);
  float hh = fmaxf((float)(y1 - y0 + 1), 1.0f);
  float wd = fmaxf((float)(x1 - x0 + 1), 1.0f);
  InstP p;
  p.y0 = y0; p.x0 = x0; p.y1r = y1r; p.x1r = x1r;
  p.ys = max(y0, 0); p.ye = min(y1 + 1, Hh);
  p.xs = max(x0, 0); p.xe = min(x1 + 1, Ww);
  p.sc_y = 28.0f / hh; p.sc_x = 28.0f / wd;
  int cl = cls[b*Nn + n];
  p.tc = NSs + cl;
  p.mskoff = (((b*Nn + n)*NTs) + cl)*Rr*Rr;
  spar[n] = p;
}

__global__ void k_zero(int* __restrict__ p, int n) {
  for (int i = threadIdx.x; i < n; i += 256) p[i] = 0;
}

// EXACT R7 k_fuse (best measured: under the 42us fills, occ ~50%).
// R11 post-mortem: float4/4-contig-px widened the gating window 64->256 px and
// cut occupancy (192 thr) -> 50us regression. Scalar loads + stride-256 px
// keep each wave on a contiguous 64-px window -> tight relw + cheap __any.
__global__ __launch_bounds__(256) void k_fuse(
    const float* __restrict__ sem, const float* __restrict__ roi,
    const float* __restrict__ bbx, const int* __restrict__ cls,
    int* __restrict__ out_pred, int* __restrict__ g_hist, int* __restrict__ g_scount)
{
  __shared__ InstP spar[Nn];
  __shared__ int s_all[NKEY];
  __shared__ unsigned s_rel;
  __shared__ int s_xlo[Nn], s_xhi[Nn];

  const int bid  = blockIdx.x;
  const int y    = bid % Hh;
  const int b    = bid / Hh;
  const int tid  = threadIdx.x;
  const int lane = tid & 63;

  if (tid == 0) s_rel = 0u;
  for (int i = tid; i < NKEY; i += 256) s_all[i] = 0;
  if (tid < Nn) {
    setup_inst(b, tid, bbx, cls, spar);
    const InstP p = spar[tid];
    s_xlo[tid] = min(p.x0, p.xs);        // union x-interval (conservative gate)
    s_xhi[tid] = max(p.x1r, p.xe);
    bool rowi = (y >= p.y0) && (y < p.y1r);
    bool rowm = (y >= p.ys) && (y < p.ye);
    if (rowi || rowm) atomicOr(&s_rel, 1u << tid);
  }
  __syncthreads();

  const double EPS = (sigd(NEGD) + sigd(NEGD)) * (NEGD + NEGD);
  const float* base = sem + (size_t)b*Cch*HW + (size_t)y*Ww;

  const int  li   = lane & 31;
  const int  gxlo = s_xlo[li];
  const int  gxhi = s_xhi[li];
  const bool grow = (lane < 32) && ((s_rel >> li) & 1u);

  float cur[Cch], nxt[Cch];
#pragma unroll
  for (int c = 0; c < Cch; c++) cur[c] = base[(size_t)c*HW + tid];

  for (int ck = 0; ck < 3; ck++) {
    const int x = ck*256 + tid;
    if (ck < 2) {
#pragma unroll
      for (int c = 0; c < Cch; c++) nxt[c] = base[(size_t)c*HW + x + 256];
    }
    const int xa = x & ~63;   // wave's 64-px window base (uniform per wave)
    unsigned relw = (unsigned)__ballot(grow && (gxlo < xa + 64) && (gxhi > xa));

    int smp;
    int pidx = fuse_px(y, x, cur, relw, spar, roi, EPS, &smp);
    out_pred[(size_t)b*HW + (size_t)y*Ww + x] = pidx;
    atomicAdd(&s_all[(pidx >= NSs) ? ((pidx - NSs)*Cch + smp) : (Nn*Cch + pidx)], 1);

    if (ck < 2) {
#pragma unroll
      for (int c = 0; c < Cch; c++) cur[c] = nxt[c];
    }
  }

  __syncthreads();
  for (int i = tid; i < NKEY; i += 256) {
    int v = s_all[i];
    if (v) {
      if (i < Nn*Cch) atomicAdd(&g_hist[b*Nn*Cch + i], v);
      else            atomicAdd(&g_scount[b*NSs + (i - Nn*Cch)], v);
    }
  }
}

// merged post+seam (verified bit-exact in R11): every block recomputes the
// tiny post logic from the L2-hot 652-int hist (ballot/popcount, no scratch),
// builds slut in LDS, block 0 also writes the tail, then int4-remaps its slice.
// All __syncthreads() reached by ALL 256 threads (R8 post-mortem).
__global__ __launch_bounds__(256) void k_seam2(
    int* __restrict__ pred, const int* __restrict__ g_hist,
    const int* __restrict__ g_scount, const int* __restrict__ cls,
    int* __restrict__ out_tail)
{
  __shared__ int sh[Bb*Nn*Cch];
  __shared__ int spc_f[Bb][NSs];
  __shared__ int pcf[Bb][40];
  __shared__ int slut[Bb*NCH];
  const int t = threadIdx.x;
  for (int i = t; i < Bb*Nn*Cch; i += 256) sh[i] = g_hist[i];
  if (t < Bb*NSs) spc_f[t/NSs][t%NSs] = g_scount[t];
  __syncthreads();

  const int  b    = t >> 6;        // waves 2,3 inactive (bv=false), barrier-uniform
  const int  lane = t & 63;
  const int  bs   = b & 1;         // safe LDS index for inactive waves
  const bool bv   = b < Bb;
  const bool act  = bv && (lane < Nn);

  int total = 0, mi = 0, mx = -1, tmp = 0;
  bool br2 = false, kept = false;
  if (act) {
    const int* hb = sh + b*Nn*Cch + lane*Cch;
#pragma unroll
    for (int c = 0; c < Cch; c++) { int v = hb[c]; total += v; if (v > mx) { mx = v; mi = c; } }
    tmp = cls[b*Nn + lane] + NSs;
    bool present = total > 0;
    bool b1 = (mi == tmp);
    br2  = (!b1) && (2*mx >= total) && (mi < NSs) && present;
    kept = present && !br2;
    if (br2) atomicAdd(&spc_f[b][mi], total);
  }
  __syncthreads();

  unsigned mask6 = (unsigned)(__ballot(bv && lane < NSs && spc_f[bs][lane] > 0) & 0x3Full);
  int nstuff = __popc(mask6);
  unsigned kmask = (unsigned)(__ballot(act && kept) & 0xFFFFFFFFull);
  int nk = __popc(kmask);
  int vlen = 1 + nstuff + nk;

  if (bv && lane < NSs)
    slut[b*NCH + lane] = __popc(mask6 & ((1u << lane) - 1)) + 1;  // absent: unused
  if (act) {
    int rk     = __popc(kmask & ((1u << lane) - 1));
    int srk_mi = __popc(mask6 & ((1u << mi) - 1));
    slut[b*NCH + NSs + lane] = kept ? (1 + nstuff + rk) : (br2 ? srk_mi + 1 : 0);
  }
  if (bv && lane < 39) pcf[b][lane] = -1;
  __syncthreads();
  if (bv && lane == 0) pcf[b][0] = 255;
  if (bv && lane < NSs && ((mask6 >> lane) & 1))
    pcf[b][1 + __popc(mask6 & ((1u << lane) - 1))] = lane;
  if (act && kept)
    pcf[b][1 + nstuff + __popc(kmask & ((1u << lane) - 1))] = tmp;
  __syncthreads();

  if (blockIdx.x == 0) {               // tail written once (no barriers inside)
    int* pc = out_tail;                // po_cls   [Bb][39]
    int* ic = out_tail + Bb*39;        // iscrowd  [Bb][39]
    int* vl = out_tail + 2*Bb*39;      // valid_len[Bb]
    if (bv && lane < 39) {
      pc[b*39 + lane] = pcf[b][lane];
      ic[b*39 + lane] = (lane < vlen) ? 0 : -1;
    }
    if (bv && lane == 0) vl[b] = vlen;
  }

  size_t i = ((size_t)blockIdx.x*256 + t) * 4;
  int bb = (int)(i / HW);              // HW divisible by 4: no straddle
  int4 v = *reinterpret_cast<int4*>(pred + i);
  int bo = bb*NCH;
  v.x = slut[bo + v.x];
  v.y = slut[bo + v.y];
  v.z = slut[bo + v.z];
  v.w = slut[bo + v.w];
  *reinterpret_cast<int4*>(pred + i) = v;
}

extern "C" void kernel_launch(void* const* d_in, const int* in_sizes, int n_in,
                              void* d_out, int out_size, void* d_ws, size_t ws_size,
                              hipStream_t stream)
{
  const float* sem = (const float*)d_in[0];
  const float* roi = (const float*)d_in[1];
  const float* bbx = (const float*)d_in[2];
  const int*   cls = (const int*)d_in[3];
  int* out = (int*)d_out;

  int* g_hist   = (int*)d_ws;                 // Bb*Nn*Cch = 640
  int* g_scount = g_hist + Bb*Nn*Cch;         // Bb*NSs   = 12

  k_zero<<<1, 256, 0, stream>>>(g_hist, Bb*Nn*Cch + Bb*NSs);
  k_fuse<<<dim3(Bb*Hh), 256, 0, stream>>>(sem, roi, bbx, cls, out, g_hist, g_scount);
  k_seam2<<<dim3((Bb*HW)/(256*4)), 256, 0, stream>>>(out, g_hist, g_scount, cls,
                                                     out + (size_t)Bb*HW);
}